// Round 9
// baseline (147.802 us; speedup 1.0000x reference)
//
#include <hip/hip_runtime.h>
#include <math.h>

// Live dataflow (softmax over singleton axis == 1.0):
//   x (64,8,2048) -> conv1(16,1,3,5 pad(1,2)) +bias,relu -> maxpool W/2 -> (64,16,8,1024)
//   -> conv2(32,16,3,5 pad(1,2)) +bias,relu -> maxpool W/2 -> mean(H,W) -> g (64,32)
//   -> glob = LN(relu(g@w_glob+b_glob)) -> v = glob@wv.T+bv -> ao = v@out_w.T+out_b
//   -> hmid = relu(ao@mlp_w1+mlp_b1) -> out = hmid@mlp_w2+mlp_b2  (64,10)
//
// Round 9: conv split into two homogeneous kernels through global fp16 h1 (L3-resident).
// conv2 numerics: single-product fp16 MFMA 32x32x16 (validated r6/r8: absmax 1.2e-4).

typedef __attribute__((ext_vector_type(4))) _Float16 f16x4;
typedef __attribute__((ext_vector_type(8)))  _Float16 f16x8;
typedef __attribute__((ext_vector_type(16))) float    f32x16;

#define WPAD 1028           // h1g padded width: wpad = w + 2, zeros at 0,1,1026,1027

template <int CTRL>
__device__ __forceinline__ float dppf(float v) {
    return __uint_as_float(__builtin_amdgcn_update_dpp(
        0u, __float_as_uint(v), CTRL, 0xF, 0xF, true));
}
#define DPP_XOR1 0xB1       // quad_perm [1,0,3,2]
#define DPP_XOR2 0x4E       // quad_perm [2,3,0,1]
#define DPP_ROR4 0x124      // row_ror:4
#define DPP_ROR8 0x128      // row_ror:8

// ---------------- kernel A: conv1 + relu + maxpool -> h1g (fp16), frag prep folded ----
__global__ __launch_bounds__(256, 2) void conv1_kernel(
    const float* __restrict__ x,
    const float* __restrict__ w1, const float* __restrict__ b1,
    const float* __restrict__ w2,
    _Float16* __restrict__ fragg,      // [15][64][8]
    _Float16* __restrict__ h1g)        // [64 b][8 r][1028 wpad][16 ic]
{
    const int blk = blockIdx.x;        // 0..511
    const int b   = blk >> 3;
    const int r   = blk & 7;
    const int tid = threadIdx.x;       // 0..255

    __shared__ __align__(16) float xrow[3][2056];   // rows r-1..r+1, col idx = c+2

    for (int i = tid; i < 3 * 2056; i += 256) {
        int q = i / 2056, ci = i - q * 2056;
        int c = ci - 2;
        int rr = r + q - 1;
        float v = 0.f;
        if (rr >= 0 && rr < 8 && c >= 0 && c < 2048) v = x[(b * 8 + rr) * 2048 + c];
        xrow[q][ci] = v;
    }

    // fold in conv2-weight fragment build (blocks 0..14, one tap each)
    if (blk < 15 && tid < 64) {
        const int t = blk, lane = tid;
        const int kh = t / 5, kw = t - kh * 5;
        const int oc = lane & 31;
        const int ic0 = (lane >> 5) * 8;
        f16x8 hv;
        #pragma unroll
        for (int j = 0; j < 8; ++j)
            hv[j] = (_Float16)w2[((oc * 16 + ic0 + j) * 3 + kh) * 5 + kw];
        *(f16x8*)&fragg[(t * 64 + lane) * 8] = hv;
    }
    __syncthreads();

    // thread computes pooled cols wp0..wp0+3 for all 16 ic
    const int wp0 = tid * 4;
    float xl[3][16];
    #pragma unroll
    for (int q = 0; q < 3; ++q) {
        const float4* p = (const float4*)&xrow[q][8 * tid];   // idx 8t..8t+15 (= cols 2wp0-2..)
        float4 a0 = p[0], a1 = p[1], a2 = p[2], a3 = p[3];
        xl[q][0]=a0.x; xl[q][1]=a0.y; xl[q][2]=a0.z; xl[q][3]=a0.w;
        xl[q][4]=a1.x; xl[q][5]=a1.y; xl[q][6]=a1.z; xl[q][7]=a1.w;
        xl[q][8]=a2.x; xl[q][9]=a2.y; xl[q][10]=a2.z; xl[q][11]=a2.w;
        xl[q][12]=a3.x; xl[q][13]=a3.y; xl[q][14]=a3.z; xl[q][15]=a3.w;
    }

    f16x8 o0[4], o1[4];                 // [d][ic<8], [d][ic-8]
    for (int ic = 0; ic < 16; ++ic) {   // wave-uniform w1 -> scalar loads
        const float bb = b1[ic];
        float wv[15];
        #pragma unroll
        for (int k = 0; k < 15; ++k) wv[k] = w1[ic * 15 + k];
        #pragma unroll
        for (int d = 0; d < 4; ++d) {
            float c0 = bb, c1 = bb;
            #pragma unroll
            for (int kh = 0; kh < 3; ++kh)
                #pragma unroll
                for (int kw = 0; kw < 5; ++kw) {
                    float w = wv[kh * 5 + kw];
                    c0 = fmaf(xl[kh][2 * d + kw],     w, c0);
                    c1 = fmaf(xl[kh][2 * d + kw + 1], w, c1);
                }
            float v = fmaxf(fmaxf(c0, c1), 0.f);
            if (ic < 8) o0[d][ic] = (_Float16)v; else o1[d][ic - 8] = (_Float16)v;
        }
    }

    _Float16* base = &h1g[(((size_t)b * 8 + r) * WPAD + wp0 + 2) * 16];
    #pragma unroll
    for (int d = 0; d < 4; ++d) {
        *(f16x8*)&base[d * 16]     = o0[d];
        *(f16x8*)&base[d * 16 + 8] = o1[d];
    }
    // zero margins (wpad 0,1 and 1026,1027)
    if (tid == 0 || tid == 255) {
        _Float16* mb = &h1g[(((size_t)b * 8 + r) * WPAD + (tid ? 1026 : 0)) * 16];
        f16x8 z = {};
        *(f16x8*)&mb[0] = z; *(f16x8*)&mb[8] = z;
        *(f16x8*)&mb[16] = z; *(f16x8*)&mb[24] = z;
    }
}

// ---------------- kernel B: conv2 via fp16 MFMA + pool/mean epilogue -----------------
__global__ __launch_bounds__(256, 4) void conv2_kernel(
    const _Float16* __restrict__ h1g,
    const float* __restrict__ b2,
    const _Float16* __restrict__ fragg,
    float* __restrict__ part)          // [64 b][32 oc][16 wt][4 wave][2 nhalf]
{
    const int wt  = blockIdx.x;        // 0..15
    const int b   = blockIdx.y;        // 0..63
    const int tid = threadIdx.x;
    const int w0  = wt * 64;

    __shared__ __align__(16) _Float16 h1[10 * 68 * 16];   // [(rr*68+c)*16+ic], rr 0,9 zero

    {
        unsigned int* hh = (unsigned int*)h1;
        for (int i = tid; i < 544; i += 256) {            // 68*16*2/4 = 544 dwords per row
            hh[i] = 0u; hh[9 * 544 + i] = 0u;
        }
    }
    // stage rows 1..8: tile col c=0..67 <-> wpad = w0 + c ; 136 x 16B chunks per row
    for (int i = tid; i < 8 * 136; i += 256) {
        int row = i / 136, ch = i - row * 136;
        float4 v = *(const float4*)&h1g[(((size_t)b * 8 + row) * WPAD + w0) * 16 + ch * 8];
        *(float4*)&h1[(row + 1) * 1088 + ch * 8] = v;
    }
    __syncthreads();

    const int lane  = tid & 63;
    const int wave  = tid >> 6;
    const int laneN = lane & 31;
    const int icoff = (lane >> 5) * 8;
    const int half  = lane >> 5;

    f32x16 acc[4];
    #pragma unroll
    for (int nt = 0; nt < 4; ++nt)
        #pragma unroll
        for (int r = 0; r < 16; ++r) acc[nt][r] = 0.f;

    const f16x8* Ag = (const f16x8*)fragg;
    f16x8 a_cur = Ag[lane];                          // tap 0 (L1/L2-resident)
    for (int t = 0; t < 15; ++t) {
        f16x8 a_nxt = (t < 14) ? Ag[(t + 1) * 64 + lane] : a_cur;  // 1-deep prefetch
        int kh = t / 5, kw = t - kh * 5;             // wave-uniform
        #pragma unroll
        for (int nt = 0; nt < 4; ++nt) {
            int hrow = 2 * wave + (nt >> 1);
            int wn0  = (nt & 1) * 32;
            int idx  = ((hrow + kh) * 68 + wn0 + laneN + kw) * 16 + icoff;
            f16x8 bv = *(const f16x8*)&h1[idx];
            acc[nt] = __builtin_amdgcn_mfma_f32_32x32x16_f16(a_cur, bv, acc[nt], 0, 0, 0);
        }
        a_cur = a_nxt;
    }

    // epilogue (VALU/DPP): +bias, relu(maxpool) via DPP xor1, 16-lane DPP sum
    float b2v[16], sums[16];
    #pragma unroll
    for (int r = 0; r < 16; ++r) {
        b2v[r]  = b2[(r & 3) + 8 * (r >> 2) + 4 * half];
        sums[r] = 0.f;
    }
    #pragma unroll
    for (int nt = 0; nt < 4; ++nt)
        #pragma unroll
        for (int r = 0; r < 16; ++r) {
            float d = acc[nt][r] + b2v[r];
            float o = fmaxf(fmaxf(d, dppf<DPP_XOR1>(d)), 0.f);   // pool pair + relu
            sums[r] += o;                                         // counts each pair twice
        }
    #pragma unroll
    for (int r = 0; r < 16; ++r) {
        float s = sums[r];
        s += dppf<DPP_XOR1>(s);
        s += dppf<DPP_XOR2>(s);
        s += dppf<DPP_ROR4>(s);
        s += dppf<DPP_ROR8>(s);      // full sum within each 16-lane group
        sums[r] = s;
    }
    if ((lane & 15) == 0) {          // lanes 0,16,32,48: two n-halves x two K-halves
        const int nh = (lane >> 4) & 1;
        #pragma unroll
        for (int r = 0; r < 16; ++r) {
            int oc = (r & 3) + 8 * (r >> 2) + 4 * half;
            part[((b * 32 + oc) * 16 + wt) * 8 + wave * 2 + nh] = 0.5f * sums[r];
        }
    }
}

// ---------------- tail: mean -> LN -> v -> out_w -> mlp ------------------------------
__global__ void tail_kernel(
    const float* __restrict__ part,
    const float* __restrict__ w_glob, const float* __restrict__ b_glob,
    const float* __restrict__ g_glob, const float* __restrict__ be_glob,
    const float* __restrict__ in_proj_w, const float* __restrict__ in_proj_b,
    const float* __restrict__ out_w, const float* __restrict__ out_b,
    const float* __restrict__ mlp_w1, const float* __restrict__ mlp_b1,
    const float* __restrict__ mlp_w2, const float* __restrict__ mlp_b2,
    float* __restrict__ out)
{
    const int b = blockIdx.x;        // 0..63
    const int e = threadIdx.x;       // 0..63 (one wave)
    __shared__ float gs[32], glob_s[64], vs[64], aos[64], hms[32];

    if (e < 32) {
        float sm = 0.f;
        #pragma unroll
        for (int t = 0; t < 128; ++t) sm += part[(b * 32 + e) * 128 + t];
        gs[e] = sm * (1.f / 4096.f);  // mean over 8*512
    }
    __syncthreads();

    float acc = b_glob[e];
    #pragma unroll
    for (int i = 0; i < 32; ++i) acc = fmaf(gs[i], w_glob[i * 64 + e], acc);
    acc = fmaxf(acc, 0.f);

    float m = acc;
    #pragma unroll
    for (int k = 32; k >= 1; k >>= 1) m += __shfl_xor(m, k);
    m *= (1.f / 64.f);
    float d = acc - m;
    float vv = d * d;
    #pragma unroll
    for (int k = 32; k >= 1; k >>= 1) vv += __shfl_xor(vv, k);
    vv *= (1.f / 64.f);
    float gl = d * (1.f / sqrtf(vv + 1e-5f)) * g_glob[e] + be_glob[e];
    glob_s[e] = gl;
    __syncthreads();

    float vval = in_proj_b[128 + e];
    #pragma unroll
    for (int j = 0; j < 64; ++j) vval = fmaf(glob_s[j], in_proj_w[(128 + e) * 64 + j], vval);
    vs[e] = vval;
    __syncthreads();

    float ao = out_b[e];
    #pragma unroll
    for (int j = 0; j < 64; ++j) ao = fmaf(vs[j], out_w[e * 64 + j], ao);
    aos[e] = ao;
    __syncthreads();

    if (e < 32) {
        float hm = mlp_b1[e];
        #pragma unroll
        for (int j = 0; j < 64; ++j) hm = fmaf(aos[j], mlp_w1[j * 32 + e], hm);
        hms[e] = fmaxf(hm, 0.f);
    }
    __syncthreads();

    if (e < 10) {
        float o = mlp_b2[e];
        #pragma unroll
        for (int i = 0; i < 32; ++i) o = fmaf(hms[i], mlp_w2[i * 10 + e], o);
        out[b * 10 + e] = o;
    }
}

extern "C" void kernel_launch(void* const* d_in, const int* in_sizes, int n_in,
                              void* d_out, int out_size, void* d_ws, size_t ws_size,
                              hipStream_t stream) {
    const float* x        = (const float*)d_in[0];
    const float* conv1_w  = (const float*)d_in[6];
    const float* conv1_b  = (const float*)d_in[7];
    const float* conv2_w  = (const float*)d_in[8];
    const float* conv2_b  = (const float*)d_in[9];
    const float* w_glob   = (const float*)d_in[10];
    const float* b_glob   = (const float*)d_in[11];
    const float* g_glob   = (const float*)d_in[12];
    const float* be_glob  = (const float*)d_in[13];
    const float* in_proj_w = (const float*)d_in[14];
    const float* in_proj_b = (const float*)d_in[15];
    const float* out_w    = (const float*)d_in[16];
    const float* out_b    = (const float*)d_in[17];
    const float* mlp_w1   = (const float*)d_in[18];
    const float* mlp_b1   = (const float*)d_in[19];
    const float* mlp_w2   = (const float*)d_in[20];
    const float* mlp_b2   = (const float*)d_in[21];

    _Float16* fragg = (_Float16*)d_ws;                            // 15360 B
    float* partials = (float*)((char*)d_ws + 15360);              // 1 MB
    _Float16* h1g   = (_Float16*)((char*)d_ws + 15360 + 1048576); // 64*8*1028*16*2 = 16.9 MB

    conv1_kernel<<<512, 256, 0, stream>>>(x, conv1_w, conv1_b, conv2_w, fragg, h1g);

    dim3 grid(16, 64);
    conv2_kernel<<<grid, 256, 0, stream>>>(h1g, conv2_b, fragg, partials);

    tail_kernel<<<64, 64, 0, stream>>>(partials, w_glob, b_glob, g_glob, be_glob,
                                       in_proj_w, in_proj_b, out_w, out_b,
                                       mlp_w1, mlp_b1, mlp_w2, mlp_b2,
                                       (float*)d_out);
}